// Round 3
// baseline (918.635 us; speedup 1.0000x reference)
//
#include <hip/hip_runtime.h>
#include <hip/hip_bf16.h>
#include <math.h>

#define D_FEAT 128
#define NLAYER 3
#define BN_EPS 1e-5f
#define INV_SQRT_C 0.17677669529663687f  // 1/sqrt(32)

typedef __bf16 bf16x8 __attribute__((ext_vector_type(8)));
typedef float f32x4 __attribute__((ext_vector_type(4)));

static __device__ __forceinline__ unsigned short f2bf(float f) {
    return __builtin_bit_cast(unsigned short, __float2bfloat16(f));
}
static __device__ __forceinline__ float bfl(unsigned u) { return __uint_as_float(u << 16); }
static __device__ __forceinline__ float bfh(unsigned u) { return __uint_as_float(u & 0xffff0000u); }

// ---------------- conversions ----------------

__global__ void cvt_bf16_kernel(const float* __restrict__ src, unsigned short* __restrict__ dst,
                                size_t n4) {
    for (size_t t = (size_t)blockIdx.x * blockDim.x + threadIdx.x; t < n4;
         t += (size_t)gridDim.x * blockDim.x) {
        size_t i = t * 4;
        float4 v = *(const float4*)(src + i);
        ushort4 u;
        u.x = f2bf(v.x); u.y = f2bf(v.y); u.z = f2bf(v.z); u.w = f2bf(v.w);
        *(ushort4*)(dst + i) = u;
    }
}

// dst[l][n][k] = bf16(src[l][k][n])
__global__ void transp_cvt_kernel(const float* __restrict__ src, unsigned short* __restrict__ dst,
                                  int L, int lsrc, int ldst, int K, int Ncols) {
    int total = L * K * Ncols;
    for (int i = blockIdx.x * blockDim.x + threadIdx.x; i < total;
         i += gridDim.x * blockDim.x) {
        int l = i / (K * Ncols);
        int rem = i - l * (K * Ncols);
        int k = rem / Ncols;
        int nn = rem - k * Ncols;
        dst[(size_t)l * ldst + (size_t)nn * K + k] =
            f2bf(src[(size_t)l * lsrc + (size_t)k * Ncols + nn]);
    }
}

// ---------------- CSR build ----------------

__global__ void hist_kernel(const int* __restrict__ dst, int E, int* __restrict__ deg) {
    int e = blockIdx.x * blockDim.x + threadIdx.x;
    if (e < E) atomicAdd(&deg[dst[e]], 1);
}

__global__ __launch_bounds__(256) void scan1_kernel(const int* __restrict__ deg, int n,
                                                    int* __restrict__ rowptr,
                                                    int* __restrict__ partials) {
    int b = blockIdx.x, tid = threadIdx.x;
    int base = b * 1024 + tid * 4;
    int4 d = {0, 0, 0, 0};
    if (base + 3 < n) d = *(const int4*)(deg + base);
    else {
        if (base + 0 < n) d.x = deg[base + 0];
        if (base + 1 < n) d.y = deg[base + 1];
        if (base + 2 < n) d.z = deg[base + 2];
        if (base + 3 < n) d.w = deg[base + 3];
    }
    int p0 = d.x, p1 = p0 + d.y, p2 = p1 + d.z, p3 = p2 + d.w;
    int v = p3;
    int lane = tid & 63;
    #pragma unroll
    for (int off = 1; off < 64; off <<= 1) {
        int t = __shfl_up(v, off);
        if (lane >= off) v += t;
    }
    __shared__ int wsum[4];
    int w = tid >> 6;
    if (lane == 63) wsum[w] = v;
    __syncthreads();
    int woff = 0;
    #pragma unroll
    for (int j = 0; j < 4; ++j) if (j < w) woff += wsum[j];
    int excl = woff + v - p3;
    if (base + 0 < n) rowptr[base + 1] = excl + p0;
    if (base + 1 < n) rowptr[base + 2] = excl + p1;
    if (base + 2 < n) rowptr[base + 3] = excl + p2;
    if (base + 3 < n) rowptr[base + 4] = excl + p3;
    if (tid == 255) partials[b] = excl + p3;
    if (b == 0 && tid == 0) rowptr[0] = 0;
}

__global__ void scan2_kernel(int* __restrict__ partials, int nb) {
    int lane = threadIdx.x;
    int v = (lane < nb) ? partials[lane] : 0;
    #pragma unroll
    for (int off = 1; off < 64; off <<= 1) {
        int t = __shfl_up(v, off);
        if (lane >= off) v += t;
    }
    if (lane < nb) partials[lane] = v;  // inclusive
}

__global__ __launch_bounds__(256) void scan3_kernel(int* __restrict__ rowptr, int n,
                                                    const int* __restrict__ partials) {
    int b = blockIdx.x, tid = threadIdx.x;
    if (b == 0) return;
    int off = partials[b - 1];
    int base = b * 1024 + tid * 4;
    #pragma unroll
    for (int j = 0; j < 4; ++j) {
        int i = base + j;
        if (i < n) rowptr[i + 1] += off;
    }
}

__global__ void scatter_kernel(const int* __restrict__ src, const int* __restrict__ dst, int E,
                               const int* __restrict__ rowptr, int* __restrict__ cursor,
                               int* __restrict__ csrsrc) {
    int e = blockIdx.x * blockDim.x + threadIdx.x;
    if (e < E) {
        int d = dst[e];
        int p = atomicAdd(&cursor[d], 1);
        csrsrc[rowptr[d] + p] = src[e];
    }
}

// ---------------- degree binning (counting sort by degree) ----------------

__global__ void bin_hist_kernel(const int* __restrict__ rowptr, int n, int* __restrict__ bins) {
    int i = blockIdx.x * blockDim.x + threadIdx.x;
    if (i < n) {
        int d = rowptr[i + 1] - rowptr[i];
        if (d > 255) d = 255;
        atomicAdd(&bins[d], 1);
    }
}

__global__ void bin_scan_kernel(const int* __restrict__ bins, int* __restrict__ binoff) {
    __shared__ int sd[256];
    int tid = threadIdx.x;
    int v = bins[tid];
    sd[tid] = v;
    __syncthreads();
    for (int s = 1; s < 256; s <<= 1) {
        int t = (tid >= s) ? sd[tid - s] : 0;
        __syncthreads();
        sd[tid] += t;
        __syncthreads();
    }
    binoff[tid] = sd[tid] - v;  // exclusive
}

__global__ void order_kernel(const int* __restrict__ rowptr, int n,
                             const int* __restrict__ binoff, int* __restrict__ bincur,
                             int* __restrict__ order) {
    int i = blockIdx.x * blockDim.x + threadIdx.x;
    if (i < n) {
        int d = rowptr[i + 1] - rowptr[i];
        if (d > 255) d = 255;
        int pos = binoff[d] + atomicAdd(&bincur[d], 1);
        order[pos] = i;
    }
}

// ---------------- MFMA GEMM ----------------

#define LDSS 72  // shorts per LDS row (64 data + 8 pad)

__global__ __launch_bounds__(256) void gemm_qkvs_kernel(
    const unsigned short* __restrict__ A, int M,
    const unsigned short* __restrict__ Wt,
    const float* __restrict__ b0, const float* __restrict__ b1,
    const float* __restrict__ b2, const float* __restrict__ b3,
    float* __restrict__ q, unsigned short* __restrict__ kv, float* __restrict__ s)
{
    __shared__ unsigned short As[128 * LDSS];
    __shared__ unsigned short Bs[128 * LDSS];
    int rt = blockIdx.x, ct = blockIdx.y;
    int r0 = rt * 128;
    const unsigned short* W = Wt + (size_t)ct * 16384;
    const float* bias = (ct == 0) ? b0 : (ct == 1) ? b1 : (ct == 2) ? b2 : b3;
    int tid = threadIdx.x;
    int wid = tid >> 6, lane = tid & 63;
    int wm = wid >> 1, wn = wid & 1;
    int lr = lane & 15, lk = lane >> 4;

    f32x4 acc[4][4] = {};

    for (int kk = 0; kk < 128; kk += 64) {
        int row = tid >> 3;
        int c8 = (tid & 7) * 8;
        #pragma unroll
        for (int it = 0; it < 4; ++it) {
            int rr = row + it * 32;
            int gr = r0 + rr;
            int4 val = {0, 0, 0, 0};
            if (gr < M) val = *(const int4*)(A + (size_t)gr * 128 + kk + c8);
            *(int4*)(&As[rr * LDSS + c8]) = val;
        }
        #pragma unroll
        for (int it = 0; it < 4; ++it) {
            int rr = row + it * 32;
            int4 val = *(const int4*)(W + (size_t)rr * 128 + kk + c8);
            *(int4*)(&Bs[rr * LDSS + c8]) = val;
        }
        __syncthreads();

        bf16x8 a[4][2], b[4][2];
        #pragma unroll
        for (int mi = 0; mi < 4; ++mi)
            #pragma unroll
            for (int ks = 0; ks < 2; ++ks)
                a[mi][ks] = *(const bf16x8*)(&As[(wm * 64 + mi * 16 + lr) * LDSS + ks * 32 + lk * 8]);
        #pragma unroll
        for (int nj = 0; nj < 4; ++nj)
            #pragma unroll
            for (int ks = 0; ks < 2; ++ks)
                b[nj][ks] = *(const bf16x8*)(&Bs[(wn * 64 + nj * 16 + lr) * LDSS + ks * 32 + lk * 8]);
        #pragma unroll
        for (int ks = 0; ks < 2; ++ks)
            #pragma unroll
            for (int mi = 0; mi < 4; ++mi)
                #pragma unroll
                for (int nj = 0; nj < 4; ++nj)
                    acc[mi][nj] = __builtin_amdgcn_mfma_f32_16x16x32_bf16(
                        a[mi][ks], b[nj][ks], acc[mi][nj], 0, 0, 0);
        __syncthreads();
    }

    #pragma unroll
    for (int mi = 0; mi < 4; ++mi) {
        #pragma unroll
        for (int nj = 0; nj < 4; ++nj) {
            int col = wn * 64 + nj * 16 + lr;
            float bv = bias[col];
            #pragma unroll
            for (int reg = 0; reg < 4; ++reg) {
                int rw = r0 + wm * 64 + mi * 16 + lk * 4 + reg;
                if (rw < M) {
                    float val = acc[mi][nj][reg] + bv;
                    if (ct == 0) q[(size_t)rw * 128 + col] = val;
                    else if (ct == 1) kv[(size_t)rw * 256 + col] = f2bf(val);
                    else if (ct == 2) kv[(size_t)rw * 256 + 128 + col] = f2bf(val);
                    else s[(size_t)rw * 128 + col] = val;
                }
            }
        }
    }
}

__global__ __launch_bounds__(256) void gemm_final_kernel(
    const unsigned short* __restrict__ A, int M,
    const unsigned short* __restrict__ Wot, const float* __restrict__ bias,
    float* __restrict__ out)
{
    __shared__ unsigned short As[128 * LDSS];
    __shared__ unsigned short Bs[64 * LDSS];
    int r0 = blockIdx.x * 128;
    int tid = threadIdx.x;
    int wid = tid >> 6, lane = tid & 63;
    int wm = wid >> 1, wn = wid & 1;
    int lr = lane & 15, lk = lane >> 4;

    f32x4 acc[4][2] = {};

    for (int kk = 0; kk < 128; kk += 64) {
        int row = tid >> 3;
        int c8 = (tid & 7) * 8;
        #pragma unroll
        for (int it = 0; it < 4; ++it) {
            int rr = row + it * 32;
            int gr = r0 + rr;
            int4 val = {0, 0, 0, 0};
            if (gr < M) val = *(const int4*)(A + (size_t)gr * 128 + kk + c8);
            *(int4*)(&As[rr * LDSS + c8]) = val;
        }
        #pragma unroll
        for (int it = 0; it < 2; ++it) {
            int rr = row + it * 32;
            int4 val = *(const int4*)(Wot + (size_t)rr * 128 + kk + c8);
            *(int4*)(&Bs[rr * LDSS + c8]) = val;
        }
        __syncthreads();

        bf16x8 a[4][2], b[2][2];
        #pragma unroll
        for (int mi = 0; mi < 4; ++mi)
            #pragma unroll
            for (int ks = 0; ks < 2; ++ks)
                a[mi][ks] = *(const bf16x8*)(&As[(wm * 64 + mi * 16 + lr) * LDSS + ks * 32 + lk * 8]);
        #pragma unroll
        for (int nj = 0; nj < 2; ++nj)
            #pragma unroll
            for (int ks = 0; ks < 2; ++ks)
                b[nj][ks] = *(const bf16x8*)(&Bs[(wn * 32 + nj * 16 + lr) * LDSS + ks * 32 + lk * 8]);
        #pragma unroll
        for (int ks = 0; ks < 2; ++ks)
            #pragma unroll
            for (int mi = 0; mi < 4; ++mi)
                #pragma unroll
                for (int nj = 0; nj < 2; ++nj)
                    acc[mi][nj] = __builtin_amdgcn_mfma_f32_16x16x32_bf16(
                        a[mi][ks], b[nj][ks], acc[mi][nj], 0, 0, 0);
        __syncthreads();
    }

    #pragma unroll
    for (int mi = 0; mi < 4; ++mi) {
        #pragma unroll
        for (int nj = 0; nj < 2; ++nj) {
            int col = wn * 32 + nj * 16 + lr;
            float bv = bias[col];
            #pragma unroll
            for (int reg = 0; reg < 4; ++reg) {
                int rw = r0 + wm * 64 + mi * 16 + lk * 4 + reg;
                if (rw < M) out[(size_t)rw * 64 + col] = acc[mi][nj][reg] + bv;
            }
        }
    }
}

// ---------------- Fused flash-style attention: 4 nodes per wave ----------------
// 16 lanes per node, lane owns 8 channels; head = 4 lanes (32 ch).
// kv row layout: [k(128 bf16) | v(128 bf16)] = 512 B per node.

__global__ __launch_bounds__(256) void attn_kernel(
    const float* __restrict__ q, const unsigned short* __restrict__ kv,
    const float* __restrict__ sk,
    const int* __restrict__ rowptr, const int* __restrict__ csrsrc,
    const int* __restrict__ order,
    float* __restrict__ hnext, int N)
{
    int wave = (blockIdx.x * blockDim.x + threadIdx.x) >> 6;
    int lane = threadIdx.x & 63;
    int gl = lane & 15;           // lane within node group
    int slot = wave * 4 + (lane >> 4);
    bool nv = slot < N;
    int n = nv ? order[slot] : 0;

    int r0 = rowptr[n], r1 = rowptr[n + 1];
    int deg = nv ? (r1 - r0) : 0;
    int dmax = deg;
    dmax = max(dmax, __shfl_xor(dmax, 16));
    dmax = max(dmax, __shfl_xor(dmax, 32));

    const float* qp = q + (size_t)n * 128 + gl * 8;
    float4 qa = *(const float4*)(qp);
    float4 qb = *(const float4*)(qp + 4);

    float m = -INFINITY, ssum = 0.f;
    float acc[8] = {};

    for (int i = 0; i < dmax; i += 2) {
        bool a0 = i < deg, a1 = (i + 1) < deg;
        int s0 = a0 ? csrsrc[r0 + i] : 0;
        int s1 = a1 ? csrsrc[r0 + i + 1] : 0;
        const unsigned short* row0 = kv + (size_t)s0 * 256 + gl * 8;
        const unsigned short* row1 = kv + (size_t)s1 * 256 + gl * 8;
        int4 k0 = *(const int4*)(row0);
        int4 v0 = *(const int4*)(row0 + 128);
        int4 k1 = *(const int4*)(row1);
        int4 v1 = *(const int4*)(row1 + 128);

        float p0 = qa.x * bfl(k0.x) + qa.y * bfh(k0.x)
                 + qa.z * bfl(k0.y) + qa.w * bfh(k0.y)
                 + qb.x * bfl(k0.z) + qb.y * bfh(k0.z)
                 + qb.z * bfl(k0.w) + qb.w * bfh(k0.w);
        float p1 = qa.x * bfl(k1.x) + qa.y * bfh(k1.x)
                 + qa.z * bfl(k1.y) + qa.w * bfh(k1.y)
                 + qb.x * bfl(k1.z) + qb.y * bfh(k1.z)
                 + qb.z * bfl(k1.w) + qb.w * bfh(k1.w);
        p0 += __shfl_xor(p0, 1); p1 += __shfl_xor(p1, 1);
        p0 += __shfl_xor(p0, 2); p1 += __shfl_xor(p1, 2);

        float sc0 = a0 ? p0 * INV_SQRT_C : -INFINITY;
        float sc1 = a1 ? p1 * INV_SQRT_C : -INFINITY;
        float mn = fmaxf(m, fmaxf(sc0, sc1));
        if (mn > m) {
            float scale = __expf(m - mn);
            ssum *= scale;
            #pragma unroll
            for (int c = 0; c < 8; ++c) acc[c] *= scale;
            m = mn;
        }
        float e0 = a0 ? __expf(sc0 - m) : 0.f;
        float e1 = a1 ? __expf(sc1 - m) : 0.f;
        ssum += e0 + e1;
        acc[0] += e0 * bfl(v0.x) + e1 * bfl(v1.x);
        acc[1] += e0 * bfh(v0.x) + e1 * bfh(v1.x);
        acc[2] += e0 * bfl(v0.y) + e1 * bfl(v1.y);
        acc[3] += e0 * bfh(v0.y) + e1 * bfh(v1.y);
        acc[4] += e0 * bfl(v0.z) + e1 * bfl(v1.z);
        acc[5] += e0 * bfh(v0.z) + e1 * bfh(v1.z);
        acc[6] += e0 * bfl(v0.w) + e1 * bfl(v1.w);
        acc[7] += e0 * bfh(v0.w) + e1 * bfh(v1.w);
    }

    if (nv) {
        float inv = (ssum > 0.f) ? 1.0f / ssum : 0.f;
        const float* skp = sk + (size_t)n * 128 + gl * 8;
        float4 s0 = *(const float4*)(skp);
        float4 s1 = *(const float4*)(skp + 4);
        float4 o0, o1;
        o0.x = acc[0] * inv + s0.x; o0.y = acc[1] * inv + s0.y;
        o0.z = acc[2] * inv + s0.z; o0.w = acc[3] * inv + s0.w;
        o1.x = acc[4] * inv + s1.x; o1.y = acc[5] * inv + s1.y;
        o1.z = acc[6] * inv + s1.z; o1.w = acc[7] * inv + s1.w;
        float* op = hnext + (size_t)n * 128 + gl * 8;
        *(float4*)(op) = o0;
        *(float4*)(op + 4) = o1;
    }
}

// ---------------- BatchNorm ----------------

__global__ __launch_bounds__(256) void bn_stats_kernel(const float* __restrict__ x, int N, int F,
                                                       float* __restrict__ stats) {
    int tid = threadIdx.x;
    int F4 = F >> 2;
    int c4 = tid & (F4 - 1);
    int rpi = 256 / F4;
    int r = blockIdx.x * rpi + (tid / F4);
    int rstep = gridDim.x * rpi;
    float sx = 0, sy = 0, sz = 0, sw = 0, qx = 0, qy = 0, qz = 0, qw = 0;
    for (; r < N; r += rstep) {
        float4 v = *(const float4*)(x + (size_t)r * F + c4 * 4);
        sx += v.x; sy += v.y; sz += v.z; sw += v.w;
        qx += v.x * v.x; qy += v.y * v.y; qz += v.z * v.z; qw += v.w * v.w;
    }
    __shared__ float4 ls[256], lq[256];
    ls[tid] = make_float4(sx, sy, sz, sw);
    lq[tid] = make_float4(qx, qy, qz, qw);
    __syncthreads();
    if (tid < F4) {
        for (int c = F4; c < 256; c += F4) {
            float4 a = ls[tid + c], b = lq[tid + c];
            sx += a.x; sy += a.y; sz += a.z; sw += a.w;
            qx += b.x; qy += b.y; qz += b.z; qw += b.w;
        }
        atomicAdd(&stats[tid * 4 + 0], sx);
        atomicAdd(&stats[tid * 4 + 1], sy);
        atomicAdd(&stats[tid * 4 + 2], sz);
        atomicAdd(&stats[tid * 4 + 3], sw);
        atomicAdd(&stats[512 + tid * 4 + 0], qx);
        atomicAdd(&stats[512 + tid * 4 + 1], qy);
        atomicAdd(&stats[512 + tid * 4 + 2], qz);
        atomicAdd(&stats[512 + tid * 4 + 3], qw);
    }
}

__global__ void bn_finalize_kernel(float* __restrict__ stats, const float* __restrict__ g,
                                   const float* __restrict__ b, int N, int F) {
    int f = threadIdx.x;
    if (f < F) {
        float invN = 1.0f / (float)N;
        float mu = stats[f] * invN;
        float var = stats[512 + f] * invN - mu * mu;
        float sc = rsqrtf(var + BN_EPS) * g[f];
        stats[256 + f] = sc;
        stats[768 + f] = b[f] - mu * sc;
    }
}

__global__ void bn_apply_bf16_kernel(const float* __restrict__ x, unsigned short* __restrict__ y,
                                     const float* __restrict__ stats, int N, int F) {
    const float* scale = stats + 256;
    const float* shift = stats + 768;
    size_t total4 = (size_t)N * F >> 2;
    int Fm = F - 1;
    for (size_t t = (size_t)blockIdx.x * blockDim.x + threadIdx.x; t < total4;
         t += (size_t)gridDim.x * blockDim.x) {
        size_t i = t * 4;
        int f = (int)(i & (size_t)Fm);
        float4 v = *(const float4*)(x + i);
        float r0 = fmaxf(v.x * scale[f + 0] + shift[f + 0], 0.f);
        float r1 = fmaxf(v.y * scale[f + 1] + shift[f + 1], 0.f);
        float r2 = fmaxf(v.z * scale[f + 2] + shift[f + 2], 0.f);
        float r3 = fmaxf(v.w * scale[f + 3] + shift[f + 3], 0.f);
        ushort4 u;
        u.x = f2bf(r0); u.y = f2bf(r1); u.z = f2bf(r2); u.w = f2bf(r3);
        *(ushort4*)(y + i) = u;
    }
}

__global__ void bn_apply_f32_kernel(const float* __restrict__ x, float* __restrict__ y,
                                    const float* __restrict__ stats, int N, int F) {
    const float* scale = stats + 256;
    const float* shift = stats + 768;
    size_t total4 = (size_t)N * F >> 2;
    int Fm = F - 1;
    for (size_t t = (size_t)blockIdx.x * blockDim.x + threadIdx.x; t < total4;
         t += (size_t)gridDim.x * blockDim.x) {
        size_t i = t * 4;
        int f = (int)(i & (size_t)Fm);
        float4 v = *(const float4*)(x + i);
        float4 o;
        o.x = fmaxf(v.x * scale[f + 0] + shift[f + 0], 0.f);
        o.y = fmaxf(v.y * scale[f + 1] + shift[f + 1], 0.f);
        o.z = fmaxf(v.z * scale[f + 2] + shift[f + 2], 0.f);
        o.w = fmaxf(v.w * scale[f + 3] + shift[f + 3], 0.f);
        *(float4*)(y + i) = o;
    }
}

// ---------------- launch ----------------

static inline size_t al16(size_t x) { return (x + 15) & ~(size_t)15; }

extern "C" void kernel_launch(void* const* d_in, const int* in_sizes, int n_in,
                              void* d_out, int out_size, void* d_ws, size_t ws_size,
                              hipStream_t stream) {
    const float* x    = (const float*)d_in[0];
    const int*   edge = (const int*)d_in[1];
    const float* Wq   = (const float*)d_in[2];
    const float* bq   = (const float*)d_in[3];
    const float* Wk   = (const float*)d_in[4];
    const float* bk   = (const float*)d_in[5];
    const float* Wv   = (const float*)d_in[6];
    const float* bv   = (const float*)d_in[7];
    const float* Wsk  = (const float*)d_in[8];
    const float* bsk  = (const float*)d_in[9];
    const float* bng  = (const float*)d_in[10];
    const float* bnb  = (const float*)d_in[11];
    const float* Wo   = (const float*)d_in[12];
    const float* bo   = (const float*)d_in[13];
    const float* bnog = (const float*)d_in[14];
    const float* bnob = (const float*)d_in[15];

    const int N = in_sizes[0] / D_FEAT;
    const int E = in_sizes[1] / 2;
    const int* esrc = edge;
    const int* edst = edge + E;

    char* wsb = (char*)d_ws;
    unsigned short* xb = (unsigned short*)wsb; wsb += al16((size_t)N * 128 * 2);
    unsigned short* hb = (unsigned short*)wsb; wsb += al16((size_t)N * 128 * 2);
    unsigned short* kv = (unsigned short*)wsb; wsb += al16((size_t)N * 256 * 2);
    float* q      = (float*)wsb; wsb += al16((size_t)N * 128 * 4);
    float* s      = (float*)wsb; wsb += al16((size_t)N * 128 * 4);
    float* hnext  = (float*)wsb; wsb += al16((size_t)N * 128 * 4);
    float* outpre = (float*)wsb; wsb += al16((size_t)N * 64 * 4);
    unsigned short* Wt  = (unsigned short*)wsb; wsb += al16((size_t)NLAYER * 4 * 16384 * 2);
    unsigned short* Wot = (unsigned short*)wsb; wsb += al16((size_t)64 * 128 * 2);
    float* stats  = (float*)wsb; wsb += al16(1024 * 4);
    int* rowptr   = (int*)wsb;   wsb += al16((size_t)(N + 1) * 4);
    int* deg      = (int*)wsb;   wsb += al16((size_t)N * 4);
    int* csrsrc   = (int*)wsb;   wsb += al16((size_t)E * 4);
    int* partials = (int*)wsb;   wsb += al16(256 * 4);
    int* bins     = (int*)wsb;   wsb += al16(256 * 4);
    int* binoff   = (int*)wsb;   wsb += al16(256 * 4);
    int* bincur   = (int*)wsb;   wsb += al16(256 * 4);
    int* order    = (int*)wsb;   wsb += al16((size_t)N * 4);

    // conversions
    cvt_bf16_kernel<<<2048, 256, 0, stream>>>(x, xb, (size_t)N * 128 / 4);
    transp_cvt_kernel<<<256, 256, 0, stream>>>(Wq,  Wt + 0 * 16384, NLAYER, 16384, 4 * 16384, 128, 128);
    transp_cvt_kernel<<<256, 256, 0, stream>>>(Wk,  Wt + 1 * 16384, NLAYER, 16384, 4 * 16384, 128, 128);
    transp_cvt_kernel<<<256, 256, 0, stream>>>(Wv,  Wt + 2 * 16384, NLAYER, 16384, 4 * 16384, 128, 128);
    transp_cvt_kernel<<<256, 256, 0, stream>>>(Wsk, Wt + 3 * 16384, NLAYER, 16384, 4 * 16384, 128, 128);
    transp_cvt_kernel<<<64, 256, 0, stream>>>(Wo, Wot, 1, 8192, 8192, 128, 64);

    // CSR build
    const int nb1 = (N + 1023) / 1024;
    hipMemsetAsync(deg, 0, (size_t)N * 4, stream);
    hist_kernel<<<(E + 255) / 256, 256, 0, stream>>>(edst, E, deg);
    scan1_kernel<<<nb1, 256, 0, stream>>>(deg, N, rowptr, partials);
    scan2_kernel<<<1, 64, 0, stream>>>(partials, nb1);
    scan3_kernel<<<nb1, 256, 0, stream>>>(rowptr, N, partials);
    hipMemsetAsync(deg, 0, (size_t)N * 4, stream);
    scatter_kernel<<<(E + 255) / 256, 256, 0, stream>>>(esrc, edst, E, rowptr, deg, csrsrc);

    // degree-binned node order
    hipMemsetAsync(bins, 0, 256 * 4, stream);
    hipMemsetAsync(bincur, 0, 256 * 4, stream);
    bin_hist_kernel<<<(N + 255) / 256, 256, 0, stream>>>(rowptr, N, bins);
    bin_scan_kernel<<<1, 256, 0, stream>>>(bins, binoff);
    order_kernel<<<(N + 255) / 256, 256, 0, stream>>>(rowptr, N, binoff, bincur, order);

    const int gemm_rb = (N + 127) / 128;
    const int attn_blocks = (N + 15) / 16;  // 4 waves/block, 4 nodes/wave
    const unsigned short* hin = xb;
    for (int l = 0; l < NLAYER; ++l) {
        gemm_qkvs_kernel<<<dim3(gemm_rb, 4), 256, 0, stream>>>(
            hin, N, Wt + (size_t)l * 4 * 16384,
            bq + l * 128, bk + l * 128, bv + l * 128, bsk + l * 128,
            q, kv, s);
        attn_kernel<<<attn_blocks, 256, 0, stream>>>(q, kv, s, rowptr, csrsrc, order, hnext, N);
        hipMemsetAsync(stats, 0, 1024 * 4, stream);
        bn_stats_kernel<<<256, 256, 0, stream>>>(hnext, N, 128, stats);
        bn_finalize_kernel<<<1, 128, 0, stream>>>(stats, bng + l * 128, bnb + l * 128, N, 128);
        bn_apply_bf16_kernel<<<2048, 256, 0, stream>>>(hnext, hb, stats, N, 128);
        hin = hb;
    }

    gemm_final_kernel<<<gemm_rb, 256, 0, stream>>>(hb, N, Wot, bo, outpre);
    hipMemsetAsync(stats, 0, 1024 * 4, stream);
    bn_stats_kernel<<<256, 256, 0, stream>>>(outpre, N, 64, stats);
    bn_finalize_kernel<<<1, 128, 0, stream>>>(stats, bnog, bnob, N, 64);
    bn_apply_f32_kernel<<<2048, 256, 0, stream>>>(outpre, (float*)d_out, stats, N, 64);
}

// Round 4
// 645.254 us; speedup vs baseline: 1.4237x; 1.4237x over previous
//
#include <hip/hip_runtime.h>
#include <hip/hip_bf16.h>
#include <math.h>

#define D_FEAT 128
#define NLAYER 3
#define BN_EPS 1e-5f
#define INV_SQRT_C 0.17677669529663687f  // 1/sqrt(32)
#define SORT_NPB 1024                    // nodes per sort block

typedef __bf16 bf16x8 __attribute__((ext_vector_type(8)));
typedef float f32x4 __attribute__((ext_vector_type(4)));

static __device__ __forceinline__ unsigned short f2bf(float f) {
    return __builtin_bit_cast(unsigned short, __float2bfloat16(f));
}
static __device__ __forceinline__ float bfl(unsigned u) { return __uint_as_float(u << 16); }
static __device__ __forceinline__ float bfh(unsigned u) { return __uint_as_float(u & 0xffff0000u); }

// ---------------- conversions ----------------

__global__ void cvt_bf16_kernel(const float* __restrict__ src, unsigned short* __restrict__ dst,
                                size_t n4) {
    for (size_t t = (size_t)blockIdx.x * blockDim.x + threadIdx.x; t < n4;
         t += (size_t)gridDim.x * blockDim.x) {
        size_t i = t * 4;
        float4 v = *(const float4*)(src + i);
        ushort4 u;
        u.x = f2bf(v.x); u.y = f2bf(v.y); u.z = f2bf(v.z); u.w = f2bf(v.w);
        *(ushort4*)(dst + i) = u;
    }
}

// dst[l][n][k] = bf16(src[l][k][n])
__global__ void transp_cvt_kernel(const float* __restrict__ src, unsigned short* __restrict__ dst,
                                  int L, int lsrc, int ldst, int K, int Ncols) {
    int total = L * K * Ncols;
    for (int i = blockIdx.x * blockDim.x + threadIdx.x; i < total;
         i += gridDim.x * blockDim.x) {
        int l = i / (K * Ncols);
        int rem = i - l * (K * Ncols);
        int k = rem / Ncols;
        int nn = rem - k * Ncols;
        dst[(size_t)l * ldst + (size_t)nn * K + k] =
            f2bf(src[(size_t)l * lsrc + (size_t)k * Ncols + nn]);
    }
}

// ---------------- CSR build ----------------

__global__ void hist_kernel(const int* __restrict__ dst, int E, int* __restrict__ deg) {
    int e = blockIdx.x * blockDim.x + threadIdx.x;
    if (e < E) atomicAdd(&deg[dst[e]], 1);
}

__global__ __launch_bounds__(256) void scan1_kernel(const int* __restrict__ deg, int n,
                                                    int* __restrict__ rowptr,
                                                    int* __restrict__ partials) {
    int b = blockIdx.x, tid = threadIdx.x;
    int base = b * 1024 + tid * 4;
    int4 d = {0, 0, 0, 0};
    if (base + 3 < n) d = *(const int4*)(deg + base);
    else {
        if (base + 0 < n) d.x = deg[base + 0];
        if (base + 1 < n) d.y = deg[base + 1];
        if (base + 2 < n) d.z = deg[base + 2];
        if (base + 3 < n) d.w = deg[base + 3];
    }
    int p0 = d.x, p1 = p0 + d.y, p2 = p1 + d.z, p3 = p2 + d.w;
    int v = p3;
    int lane = tid & 63;
    #pragma unroll
    for (int off = 1; off < 64; off <<= 1) {
        int t = __shfl_up(v, off);
        if (lane >= off) v += t;
    }
    __shared__ int wsum[4];
    int w = tid >> 6;
    if (lane == 63) wsum[w] = v;
    __syncthreads();
    int woff = 0;
    #pragma unroll
    for (int j = 0; j < 4; ++j) if (j < w) woff += wsum[j];
    int excl = woff + v - p3;
    if (base + 0 < n) rowptr[base + 1] = excl + p0;
    if (base + 1 < n) rowptr[base + 2] = excl + p1;
    if (base + 2 < n) rowptr[base + 3] = excl + p2;
    if (base + 3 < n) rowptr[base + 4] = excl + p3;
    if (tid == 255) partials[b] = excl + p3;
    if (b == 0 && tid == 0) rowptr[0] = 0;
}

__global__ void scan2_kernel(int* __restrict__ partials, int nb) {
    int lane = threadIdx.x;
    int v = (lane < nb) ? partials[lane] : 0;
    #pragma unroll
    for (int off = 1; off < 64; off <<= 1) {
        int t = __shfl_up(v, off);
        if (lane >= off) v += t;
    }
    if (lane < nb) partials[lane] = v;  // inclusive
}

__global__ __launch_bounds__(256) void scan3_kernel(int* __restrict__ rowptr, int n,
                                                    const int* __restrict__ partials) {
    int b = blockIdx.x, tid = threadIdx.x;
    if (b == 0) return;
    int off = partials[b - 1];
    int base = b * 1024 + tid * 4;
    #pragma unroll
    for (int j = 0; j < 4; ++j) {
        int i = base + j;
        if (i < n) rowptr[i + 1] += off;
    }
}

__global__ void scatter_kernel(const int* __restrict__ src, const int* __restrict__ dst, int E,
                               const int* __restrict__ rowptr, int* __restrict__ cursor,
                               int* __restrict__ csrsrc) {
    int e = blockIdx.x * blockDim.x + threadIdx.x;
    if (e < E) {
        int d = dst[e];
        int p = atomicAdd(&cursor[d], 1);
        csrsrc[rowptr[d] + p] = src[e];
    }
}

// ---------------- degree binning: contention-free counting sort ----------------
// A: per-block LDS histogram -> bhist[d*B + b]
__global__ __launch_bounds__(256) void bin_blockhist_kernel(
    const int* __restrict__ rowptr, int n, int B, int* __restrict__ bhist)
{
    __shared__ int h[256];
    int b = blockIdx.x, tid = threadIdx.x;
    h[tid] = 0;
    __syncthreads();
    #pragma unroll
    for (int j = 0; j < SORT_NPB / 256; ++j) {
        int i = b * SORT_NPB + j * 256 + tid;
        if (i < n) {
            int d = rowptr[i + 1] - rowptr[i];
            if (d > 255) d = 255;
            atomicAdd(&h[d], 1);
        }
    }
    __syncthreads();
    bhist[tid * B + b] = h[tid];
}

// B: per-bin column scan across blocks (thread d owns bin d) + block-scan of bin
// totals -> binoff (global exclusive bin offsets). bhist becomes per-(bin,block)
// exclusive offsets within the bin. Single block of 256 threads.
__global__ __launch_bounds__(256) void bin_colscan_kernel(
    int* __restrict__ bhist, int B, int* __restrict__ binoff)
{
    int d = threadIdx.x;
    int run = 0;
    for (int b = 0; b < B; ++b) {
        int c = bhist[d * B + b];
        bhist[d * B + b] = run;
        run += c;
    }
    __shared__ int sd[256];
    sd[d] = run;
    __syncthreads();
    int v = run;
    for (int s = 1; s < 256; s <<= 1) {
        int t = (d >= s) ? sd[d - s] : 0;
        __syncthreads();
        sd[d] += t;
        __syncthreads();
    }
    binoff[d] = sd[d] - v;  // exclusive
}

// C: write order using per-block bases + LDS atomics (no global atomics)
__global__ __launch_bounds__(256) void bin_order_kernel(
    const int* __restrict__ rowptr, int n, int B,
    const int* __restrict__ bhist, const int* __restrict__ binoff,
    int* __restrict__ order)
{
    __shared__ int cur[256];
    int b = blockIdx.x, tid = threadIdx.x;
    cur[tid] = binoff[tid] + bhist[tid * B + b];
    __syncthreads();
    #pragma unroll
    for (int j = 0; j < SORT_NPB / 256; ++j) {
        int i = b * SORT_NPB + j * 256 + tid;
        if (i < n) {
            int d = rowptr[i + 1] - rowptr[i];
            if (d > 255) d = 255;
            int pos = atomicAdd(&cur[d], 1);
            order[pos] = i;
        }
    }
}

// ---------------- MFMA GEMM ----------------

#define LDSS 72  // shorts per LDS row (64 data + 8 pad)

__global__ __launch_bounds__(256) void gemm_qkvs_kernel(
    const unsigned short* __restrict__ A, int M,
    const unsigned short* __restrict__ Wt,
    const float* __restrict__ b0, const float* __restrict__ b1,
    const float* __restrict__ b2, const float* __restrict__ b3,
    float* __restrict__ q, unsigned short* __restrict__ kv, float* __restrict__ s)
{
    __shared__ unsigned short As[128 * LDSS];
    __shared__ unsigned short Bs[128 * LDSS];
    int rt = blockIdx.x, ct = blockIdx.y;
    int r0 = rt * 128;
    const unsigned short* W = Wt + (size_t)ct * 16384;
    const float* bias = (ct == 0) ? b0 : (ct == 1) ? b1 : (ct == 2) ? b2 : b3;
    int tid = threadIdx.x;
    int wid = tid >> 6, lane = tid & 63;
    int wm = wid >> 1, wn = wid & 1;
    int lr = lane & 15, lk = lane >> 4;

    f32x4 acc[4][4] = {};

    for (int kk = 0; kk < 128; kk += 64) {
        int row = tid >> 3;
        int c8 = (tid & 7) * 8;
        #pragma unroll
        for (int it = 0; it < 4; ++it) {
            int rr = row + it * 32;
            int gr = r0 + rr;
            int4 val = {0, 0, 0, 0};
            if (gr < M) val = *(const int4*)(A + (size_t)gr * 128 + kk + c8);
            *(int4*)(&As[rr * LDSS + c8]) = val;
        }
        #pragma unroll
        for (int it = 0; it < 4; ++it) {
            int rr = row + it * 32;
            int4 val = *(const int4*)(W + (size_t)rr * 128 + kk + c8);
            *(int4*)(&Bs[rr * LDSS + c8]) = val;
        }
        __syncthreads();

        bf16x8 a[4][2], b[4][2];
        #pragma unroll
        for (int mi = 0; mi < 4; ++mi)
            #pragma unroll
            for (int ks = 0; ks < 2; ++ks)
                a[mi][ks] = *(const bf16x8*)(&As[(wm * 64 + mi * 16 + lr) * LDSS + ks * 32 + lk * 8]);
        #pragma unroll
        for (int nj = 0; nj < 4; ++nj)
            #pragma unroll
            for (int ks = 0; ks < 2; ++ks)
                b[nj][ks] = *(const bf16x8*)(&Bs[(wn * 64 + nj * 16 + lr) * LDSS + ks * 32 + lk * 8]);
        #pragma unroll
        for (int ks = 0; ks < 2; ++ks)
            #pragma unroll
            for (int mi = 0; mi < 4; ++mi)
                #pragma unroll
                for (int nj = 0; nj < 4; ++nj)
                    acc[mi][nj] = __builtin_amdgcn_mfma_f32_16x16x32_bf16(
                        a[mi][ks], b[nj][ks], acc[mi][nj], 0, 0, 0);
        __syncthreads();
    }

    #pragma unroll
    for (int mi = 0; mi < 4; ++mi) {
        #pragma unroll
        for (int nj = 0; nj < 4; ++nj) {
            int col = wn * 64 + nj * 16 + lr;
            float bv = bias[col];
            #pragma unroll
            for (int reg = 0; reg < 4; ++reg) {
                int rw = r0 + wm * 64 + mi * 16 + lk * 4 + reg;
                if (rw < M) {
                    float val = acc[mi][nj][reg] + bv;
                    if (ct == 0) q[(size_t)rw * 128 + col] = val;
                    else if (ct == 1) kv[(size_t)rw * 256 + col] = f2bf(val);
                    else if (ct == 2) kv[(size_t)rw * 256 + 128 + col] = f2bf(val);
                    else s[(size_t)rw * 128 + col] = val;
                }
            }
        }
    }
}

__global__ __launch_bounds__(256) void gemm_final_kernel(
    const unsigned short* __restrict__ A, int M,
    const unsigned short* __restrict__ Wot, const float* __restrict__ bias,
    float* __restrict__ out)
{
    __shared__ unsigned short As[128 * LDSS];
    __shared__ unsigned short Bs[64 * LDSS];
    int r0 = blockIdx.x * 128;
    int tid = threadIdx.x;
    int wid = tid >> 6, lane = tid & 63;
    int wm = wid >> 1, wn = wid & 1;
    int lr = lane & 15, lk = lane >> 4;

    f32x4 acc[4][2] = {};

    for (int kk = 0; kk < 128; kk += 64) {
        int row = tid >> 3;
        int c8 = (tid & 7) * 8;
        #pragma unroll
        for (int it = 0; it < 4; ++it) {
            int rr = row + it * 32;
            int gr = r0 + rr;
            int4 val = {0, 0, 0, 0};
            if (gr < M) val = *(const int4*)(A + (size_t)gr * 128 + kk + c8);
            *(int4*)(&As[rr * LDSS + c8]) = val;
        }
        #pragma unroll
        for (int it = 0; it < 2; ++it) {
            int rr = row + it * 32;
            int4 val = *(const int4*)(Wot + (size_t)rr * 128 + kk + c8);
            *(int4*)(&Bs[rr * LDSS + c8]) = val;
        }
        __syncthreads();

        bf16x8 a[4][2], b[2][2];
        #pragma unroll
        for (int mi = 0; mi < 4; ++mi)
            #pragma unroll
            for (int ks = 0; ks < 2; ++ks)
                a[mi][ks] = *(const bf16x8*)(&As[(wm * 64 + mi * 16 + lr) * LDSS + ks * 32 + lk * 8]);
        #pragma unroll
        for (int nj = 0; nj < 2; ++nj)
            #pragma unroll
            for (int ks = 0; ks < 2; ++ks)
                b[nj][ks] = *(const bf16x8*)(&Bs[(wn * 32 + nj * 16 + lr) * LDSS + ks * 32 + lk * 8]);
        #pragma unroll
        for (int ks = 0; ks < 2; ++ks)
            #pragma unroll
            for (int mi = 0; mi < 4; ++mi)
                #pragma unroll
                for (int nj = 0; nj < 2; ++nj)
                    acc[mi][nj] = __builtin_amdgcn_mfma_f32_16x16x32_bf16(
                        a[mi][ks], b[nj][ks], acc[mi][nj], 0, 0, 0);
        __syncthreads();
    }

    #pragma unroll
    for (int mi = 0; mi < 4; ++mi) {
        #pragma unroll
        for (int nj = 0; nj < 2; ++nj) {
            int col = wn * 32 + nj * 16 + lr;
            float bv = bias[col];
            #pragma unroll
            for (int reg = 0; reg < 4; ++reg) {
                int rw = r0 + wm * 64 + mi * 16 + lk * 4 + reg;
                if (rw < M) out[(size_t)rw * 64 + col] = acc[mi][nj][reg] + bv;
            }
        }
    }
}

// ---------------- Fused flash-style attention: 4 nodes per wave ----------------
// 16 lanes per node, lane owns 8 channels; head = 4 lanes (32 ch).
// kv row layout: [k(128 bf16) | v(128 bf16)] = 512 B per node.

__global__ __launch_bounds__(256) void attn_kernel(
    const float* __restrict__ q, const unsigned short* __restrict__ kv,
    const float* __restrict__ sk,
    const int* __restrict__ rowptr, const int* __restrict__ csrsrc,
    const int* __restrict__ order,
    float* __restrict__ hnext, int N)
{
    int wave = (blockIdx.x * blockDim.x + threadIdx.x) >> 6;
    int lane = threadIdx.x & 63;
    int gl = lane & 15;           // lane within node group
    int slot = wave * 4 + (lane >> 4);
    bool nv = slot < N;
    int n = nv ? order[slot] : 0;

    int r0 = rowptr[n], r1 = rowptr[n + 1];
    int deg = nv ? (r1 - r0) : 0;
    int dmax = deg;
    dmax = max(dmax, __shfl_xor(dmax, 16));
    dmax = max(dmax, __shfl_xor(dmax, 32));

    const float* qp = q + (size_t)n * 128 + gl * 8;
    float4 qa = *(const float4*)(qp);
    float4 qb = *(const float4*)(qp + 4);

    float m = -INFINITY, ssum = 0.f;
    float acc[8] = {};

    for (int i = 0; i < dmax; i += 4) {
        bool a0 = i < deg, a1 = i + 1 < deg, a2 = i + 2 < deg, a3 = i + 3 < deg;
        int s0 = a0 ? csrsrc[r0 + i] : 0;
        int s1 = a1 ? csrsrc[r0 + i + 1] : 0;
        int s2 = a2 ? csrsrc[r0 + i + 2] : 0;
        int s3 = a3 ? csrsrc[r0 + i + 3] : 0;
        const unsigned short* row0 = kv + (size_t)s0 * 256 + gl * 8;
        const unsigned short* row1 = kv + (size_t)s1 * 256 + gl * 8;
        const unsigned short* row2 = kv + (size_t)s2 * 256 + gl * 8;
        const unsigned short* row3 = kv + (size_t)s3 * 256 + gl * 8;
        int4 k0 = *(const int4*)(row0);
        int4 k1 = *(const int4*)(row1);
        int4 k2 = *(const int4*)(row2);
        int4 k3 = *(const int4*)(row3);
        int4 v0 = *(const int4*)(row0 + 128);
        int4 v1 = *(const int4*)(row1 + 128);
        int4 v2 = *(const int4*)(row2 + 128);
        int4 v3 = *(const int4*)(row3 + 128);

        float p0 = qa.x * bfl(k0.x) + qa.y * bfh(k0.x) + qa.z * bfl(k0.y) + qa.w * bfh(k0.y)
                 + qb.x * bfl(k0.z) + qb.y * bfh(k0.z) + qb.z * bfl(k0.w) + qb.w * bfh(k0.w);
        float p1 = qa.x * bfl(k1.x) + qa.y * bfh(k1.x) + qa.z * bfl(k1.y) + qa.w * bfh(k1.y)
                 + qb.x * bfl(k1.z) + qb.y * bfh(k1.z) + qb.z * bfl(k1.w) + qb.w * bfh(k1.w);
        float p2 = qa.x * bfl(k2.x) + qa.y * bfh(k2.x) + qa.z * bfl(k2.y) + qa.w * bfh(k2.y)
                 + qb.x * bfl(k2.z) + qb.y * bfh(k2.z) + qb.z * bfl(k2.w) + qb.w * bfh(k2.w);
        float p3 = qa.x * bfl(k3.x) + qa.y * bfh(k3.x) + qa.z * bfl(k3.y) + qa.w * bfh(k3.y)
                 + qb.x * bfl(k3.z) + qb.y * bfh(k3.z) + qb.z * bfl(k3.w) + qb.w * bfh(k3.w);
        p0 += __shfl_xor(p0, 1); p1 += __shfl_xor(p1, 1);
        p2 += __shfl_xor(p2, 1); p3 += __shfl_xor(p3, 1);
        p0 += __shfl_xor(p0, 2); p1 += __shfl_xor(p1, 2);
        p2 += __shfl_xor(p2, 2); p3 += __shfl_xor(p3, 2);

        float sc0 = a0 ? p0 * INV_SQRT_C : -INFINITY;
        float sc1 = a1 ? p1 * INV_SQRT_C : -INFINITY;
        float sc2 = a2 ? p2 * INV_SQRT_C : -INFINITY;
        float sc3 = a3 ? p3 * INV_SQRT_C : -INFINITY;
        float mn = fmaxf(fmaxf(m, fmaxf(sc0, sc1)), fmaxf(sc2, sc3));
        if (mn > m) {
            float scale = __expf(m - mn);
            ssum *= scale;
            #pragma unroll
            for (int c = 0; c < 8; ++c) acc[c] *= scale;
            m = mn;
        }
        float e0 = a0 ? __expf(sc0 - m) : 0.f;
        float e1 = a1 ? __expf(sc1 - m) : 0.f;
        float e2 = a2 ? __expf(sc2 - m) : 0.f;
        float e3 = a3 ? __expf(sc3 - m) : 0.f;
        ssum += (e0 + e1) + (e2 + e3);
        acc[0] += e0 * bfl(v0.x) + e1 * bfl(v1.x) + e2 * bfl(v2.x) + e3 * bfl(v3.x);
        acc[1] += e0 * bfh(v0.x) + e1 * bfh(v1.x) + e2 * bfh(v2.x) + e3 * bfh(v3.x);
        acc[2] += e0 * bfl(v0.y) + e1 * bfl(v1.y) + e2 * bfl(v2.y) + e3 * bfl(v3.y);
        acc[3] += e0 * bfh(v0.y) + e1 * bfh(v1.y) + e2 * bfh(v2.y) + e3 * bfh(v3.y);
        acc[4] += e0 * bfl(v0.z) + e1 * bfl(v1.z) + e2 * bfl(v2.z) + e3 * bfl(v3.z);
        acc[5] += e0 * bfh(v0.z) + e1 * bfh(v1.z) + e2 * bfh(v2.z) + e3 * bfh(v3.z);
        acc[6] += e0 * bfl(v0.w) + e1 * bfl(v1.w) + e2 * bfl(v2.w) + e3 * bfl(v3.w);
        acc[7] += e0 * bfh(v0.w) + e1 * bfh(v1.w) + e2 * bfh(v2.w) + e3 * bfh(v3.w);
    }

    if (nv) {
        float inv = (ssum > 0.f) ? 1.0f / ssum : 0.f;
        const float* skp = sk + (size_t)n * 128 + gl * 8;
        float4 s0 = *(const float4*)(skp);
        float4 s1 = *(const float4*)(skp + 4);
        float4 o0, o1;
        o0.x = acc[0] * inv + s0.x; o0.y = acc[1] * inv + s0.y;
        o0.z = acc[2] * inv + s0.z; o0.w = acc[3] * inv + s0.w;
        o1.x = acc[4] * inv + s1.x; o1.y = acc[5] * inv + s1.y;
        o1.z = acc[6] * inv + s1.z; o1.w = acc[7] * inv + s1.w;
        float* op = hnext + (size_t)n * 128 + gl * 8;
        *(float4*)(op) = o0;
        *(float4*)(op + 4) = o1;
    }
}

// ---------------- BatchNorm ----------------

__global__ __launch_bounds__(256) void bn_stats_kernel(const float* __restrict__ x, int N, int F,
                                                       float* __restrict__ stats) {
    int tid = threadIdx.x;
    int F4 = F >> 2;
    int c4 = tid & (F4 - 1);
    int rpi = 256 / F4;
    int r = blockIdx.x * rpi + (tid / F4);
    int rstep = gridDim.x * rpi;
    float sx = 0, sy = 0, sz = 0, sw = 0, qx = 0, qy = 0, qz = 0, qw = 0;
    for (; r < N; r += rstep) {
        float4 v = *(const float4*)(x + (size_t)r * F + c4 * 4);
        sx += v.x; sy += v.y; sz += v.z; sw += v.w;
        qx += v.x * v.x; qy += v.y * v.y; qz += v.z * v.z; qw += v.w * v.w;
    }
    __shared__ float4 ls[256], lq[256];
    ls[tid] = make_float4(sx, sy, sz, sw);
    lq[tid] = make_float4(qx, qy, qz, qw);
    __syncthreads();
    if (tid < F4) {
        for (int c = F4; c < 256; c += F4) {
            float4 a = ls[tid + c], b = lq[tid + c];
            sx += a.x; sy += a.y; sz += a.z; sw += a.w;
            qx += b.x; qy += b.y; qz += b.z; qw += b.w;
        }
        atomicAdd(&stats[tid * 4 + 0], sx);
        atomicAdd(&stats[tid * 4 + 1], sy);
        atomicAdd(&stats[tid * 4 + 2], sz);
        atomicAdd(&stats[tid * 4 + 3], sw);
        atomicAdd(&stats[512 + tid * 4 + 0], qx);
        atomicAdd(&stats[512 + tid * 4 + 1], qy);
        atomicAdd(&stats[512 + tid * 4 + 2], qz);
        atomicAdd(&stats[512 + tid * 4 + 3], qw);
    }
}

__global__ void bn_finalize_kernel(float* __restrict__ stats, const float* __restrict__ g,
                                   const float* __restrict__ b, int N, int F) {
    int f = threadIdx.x;
    if (f < F) {
        float invN = 1.0f / (float)N;
        float mu = stats[f] * invN;
        float var = stats[512 + f] * invN - mu * mu;
        float sc = rsqrtf(var + BN_EPS) * g[f];
        stats[256 + f] = sc;
        stats[768 + f] = b[f] - mu * sc;
    }
}

__global__ void bn_apply_bf16_kernel(const float* __restrict__ x, unsigned short* __restrict__ y,
                                     const float* __restrict__ stats, int N, int F) {
    const float* scale = stats + 256;
    const float* shift = stats + 768;
    size_t total4 = (size_t)N * F >> 2;
    int Fm = F - 1;
    for (size_t t = (size_t)blockIdx.x * blockDim.x + threadIdx.x; t < total4;
         t += (size_t)gridDim.x * blockDim.x) {
        size_t i = t * 4;
        int f = (int)(i & (size_t)Fm);
        float4 v = *(const float4*)(x + i);
        float r0 = fmaxf(v.x * scale[f + 0] + shift[f + 0], 0.f);
        float r1 = fmaxf(v.y * scale[f + 1] + shift[f + 1], 0.f);
        float r2 = fmaxf(v.z * scale[f + 2] + shift[f + 2], 0.f);
        float r3 = fmaxf(v.w * scale[f + 3] + shift[f + 3], 0.f);
        ushort4 u;
        u.x = f2bf(r0); u.y = f2bf(r1); u.z = f2bf(r2); u.w = f2bf(r3);
        *(ushort4*)(y + i) = u;
    }
}

__global__ void bn_apply_f32_kernel(const float* __restrict__ x, float* __restrict__ y,
                                    const float* __restrict__ stats, int N, int F) {
    const float* scale = stats + 256;
    const float* shift = stats + 768;
    size_t total4 = (size_t)N * F >> 2;
    int Fm = F - 1;
    for (size_t t = (size_t)blockIdx.x * blockDim.x + threadIdx.x; t < total4;
         t += (size_t)gridDim.x * blockDim.x) {
        size_t i = t * 4;
        int f = (int)(i & (size_t)Fm);
        float4 v = *(const float4*)(x + i);
        float4 o;
        o.x = fmaxf(v.x * scale[f + 0] + shift[f + 0], 0.f);
        o.y = fmaxf(v.y * scale[f + 1] + shift[f + 1], 0.f);
        o.z = fmaxf(v.z * scale[f + 2] + shift[f + 2], 0.f);
        o.w = fmaxf(v.w * scale[f + 3] + shift[f + 3], 0.f);
        *(float4*)(y + i) = o;
    }
}

// ---------------- launch ----------------

static inline size_t al16(size_t x) { return (x + 15) & ~(size_t)15; }

extern "C" void kernel_launch(void* const* d_in, const int* in_sizes, int n_in,
                              void* d_out, int out_size, void* d_ws, size_t ws_size,
                              hipStream_t stream) {
    const float* x    = (const float*)d_in[0];
    const int*   edge = (const int*)d_in[1];
    const float* Wq   = (const float*)d_in[2];
    const float* bq   = (const float*)d_in[3];
    const float* Wk   = (const float*)d_in[4];
    const float* bk   = (const float*)d_in[5];
    const float* Wv   = (const float*)d_in[6];
    const float* bv   = (const float*)d_in[7];
    const float* Wsk  = (const float*)d_in[8];
    const float* bsk  = (const float*)d_in[9];
    const float* bng  = (const float*)d_in[10];
    const float* bnb  = (const float*)d_in[11];
    const float* Wo   = (const float*)d_in[12];
    const float* bo   = (const float*)d_in[13];
    const float* bnog = (const float*)d_in[14];
    const float* bnob = (const float*)d_in[15];

    const int N = in_sizes[0] / D_FEAT;
    const int E = in_sizes[1] / 2;
    const int* esrc = edge;
    const int* edst = edge + E;

    const int SB = (N + SORT_NPB - 1) / SORT_NPB;   // sort blocks

    char* wsb = (char*)d_ws;
    unsigned short* xb = (unsigned short*)wsb; wsb += al16((size_t)N * 128 * 2);
    unsigned short* hb = (unsigned short*)wsb; wsb += al16((size_t)N * 128 * 2);
    unsigned short* kv = (unsigned short*)wsb; wsb += al16((size_t)N * 256 * 2);
    float* q      = (float*)wsb; wsb += al16((size_t)N * 128 * 4);
    float* s      = (float*)wsb; wsb += al16((size_t)N * 128 * 4);
    float* hnext  = (float*)wsb; wsb += al16((size_t)N * 128 * 4);
    float* outpre = (float*)wsb; wsb += al16((size_t)N * 64 * 4);
    unsigned short* Wt  = (unsigned short*)wsb; wsb += al16((size_t)NLAYER * 4 * 16384 * 2);
    unsigned short* Wot = (unsigned short*)wsb; wsb += al16((size_t)64 * 128 * 2);
    float* stats  = (float*)wsb; wsb += al16(1024 * 4);
    int* rowptr   = (int*)wsb;   wsb += al16((size_t)(N + 1) * 4);
    int* deg      = (int*)wsb;   wsb += al16((size_t)N * 4);
    int* csrsrc   = (int*)wsb;   wsb += al16((size_t)E * 4);
    int* partials = (int*)wsb;   wsb += al16(256 * 4);
    int* bhist    = (int*)wsb;   wsb += al16((size_t)256 * SB * 4);
    int* binoff   = (int*)wsb;   wsb += al16(256 * 4);
    int* order    = (int*)wsb;   wsb += al16((size_t)N * 4);

    // conversions
    cvt_bf16_kernel<<<2048, 256, 0, stream>>>(x, xb, (size_t)N * 128 / 4);
    transp_cvt_kernel<<<256, 256, 0, stream>>>(Wq,  Wt + 0 * 16384, NLAYER, 16384, 4 * 16384, 128, 128);
    transp_cvt_kernel<<<256, 256, 0, stream>>>(Wk,  Wt + 1 * 16384, NLAYER, 16384, 4 * 16384, 128, 128);
    transp_cvt_kernel<<<256, 256, 0, stream>>>(Wv,  Wt + 2 * 16384, NLAYER, 16384, 4 * 16384, 128, 128);
    transp_cvt_kernel<<<256, 256, 0, stream>>>(Wsk, Wt + 3 * 16384, NLAYER, 16384, 4 * 16384, 128, 128);
    transp_cvt_kernel<<<64, 256, 0, stream>>>(Wo, Wot, 1, 8192, 8192, 128, 64);

    // CSR build
    const int nb1 = (N + 1023) / 1024;
    hipMemsetAsync(deg, 0, (size_t)N * 4, stream);
    hist_kernel<<<(E + 255) / 256, 256, 0, stream>>>(edst, E, deg);
    scan1_kernel<<<nb1, 256, 0, stream>>>(deg, N, rowptr, partials);
    scan2_kernel<<<1, 64, 0, stream>>>(partials, nb1);
    scan3_kernel<<<nb1, 256, 0, stream>>>(rowptr, N, partials);
    hipMemsetAsync(deg, 0, (size_t)N * 4, stream);
    scatter_kernel<<<(E + 255) / 256, 256, 0, stream>>>(esrc, edst, E, rowptr, deg, csrsrc);

    // degree-binned node order (contention-free counting sort)
    bin_blockhist_kernel<<<SB, 256, 0, stream>>>(rowptr, N, SB, bhist);
    bin_colscan_kernel<<<1, 256, 0, stream>>>(bhist, SB, binoff);
    bin_order_kernel<<<SB, 256, 0, stream>>>(rowptr, N, SB, bhist, binoff, order);

    const int gemm_rb = (N + 127) / 128;
    const int attn_blocks = (N + 15) / 16;  // 4 waves/block, 4 nodes/wave
    const unsigned short* hin = xb;
    for (int l = 0; l < NLAYER; ++l) {
        gemm_qkvs_kernel<<<dim3(gemm_rb, 4), 256, 0, stream>>>(
            hin, N, Wt + (size_t)l * 4 * 16384,
            bq + l * 128, bk + l * 128, bv + l * 128, bsk + l * 128,
            q, kv, s);
        attn_kernel<<<attn_blocks, 256, 0, stream>>>(q, kv, s, rowptr, csrsrc, order, hnext, N);
        hipMemsetAsync(stats, 0, 1024 * 4, stream);
        bn_stats_kernel<<<256, 256, 0, stream>>>(hnext, N, 128, stats);
        bn_finalize_kernel<<<1, 128, 0, stream>>>(stats, bng + l * 128, bnb + l * 128, N, 128);
        bn_apply_bf16_kernel<<<2048, 256, 0, stream>>>(hnext, hb, stats, N, 128);
        hin = hb;
    }

    gemm_final_kernel<<<gemm_rb, 256, 0, stream>>>(hb, N, Wot, bo, outpre);
    hipMemsetAsync(stats, 0, 1024 * 4, stream);
    bn_stats_kernel<<<256, 256, 0, stream>>>(outpre, N, 64, stats);
    bn_finalize_kernel<<<1, 128, 0, stream>>>(stats, bnog, bnob, N, 64);
    bn_apply_f32_kernel<<<2048, 256, 0, stream>>>(outpre, (float*)d_out, stats, N, 64);
}